// Round 5
// baseline (250.684 us; speedup 1.0000x reference)
//
#include <hip/hip_runtime.h>

// PoolingNms fused: 3 chained pool/unpool (k=3,5,6) on 16x1x1080x1920 fp32.
// After stage 1 the tensor is sparse (<=1 survivor per 3x3 cell, at its
// original position); stages 2/3 are pure filters over the survivor set.
// lcm(3,5,6)=30 | 1080,1920 -> 30x30 supertiles fully independent.
// Tie-break: packed pos (r<<5)|c ascending == row-major first-occurrence ==
// jnp.argmax, bit-exact (values >= 0, strict '>' scan).
//
// R5: minimize memory-REQUEST count (R4 post-mortem: scattered dword loads,
// not HBM bytes, were the limiter). All global traffic is full-line float4:
// cooperative load of the block's 30x120 region into LDS (~14 wave-instrs),
// scalar stage-1 reads from LDS, per-wave in-place compose of its own 30-col
// stripe, cooperative float4 store. LDS 18.75KB -> 8 blocks/CU, 32 waves.

#define IMG_H 1080
#define IMG_W 1920
#define NT 256
#define TW 120  // block tile width (4 supertiles)

__global__ __launch_bounds__(NT) void pooling_nms_kernel(
    const float* __restrict__ x, float* __restrict__ out) {
    __shared__ float tile[30 * TW];  // 14.4 KB block tile, also compose buffer
    __shared__ float sv[4][100];     // per-wave stage-1 survivor values
    __shared__ int   sp[4][100];     // packed (r<<5)|c, supertile-local
    __shared__ float w5v[4][36];     // per-wave 5x5 winners
    __shared__ int   w5p[4][36];

    const int t = threadIdx.x;
    const int w = t >> 6;   // wave 0..3 -> owns supertile cols [30w, 30w+30)
    const int ln = t & 63;

    const size_t base = (size_t)blockIdx.z * ((size_t)IMG_H * IMG_W) +
                        (size_t)blockIdx.y * 30 * IMG_W +
                        (size_t)blockIdx.x * TW;
    const float* src = x + base;
    float* dst = out + base;

    // ---- Phase 0: cooperative float4 load, global -> LDS. 900 vec4, fully
    // coalesced (block rows are 480B, 16B-aligned).
    float4* tile4 = reinterpret_cast<float4*>(tile);
    for (int i = t; i < 900; i += NT) {
        const int r = i / 30, c4 = i - (i / 30) * 30;
        tile4[i] = *reinterpret_cast<const float4*>(src + (size_t)r * IMG_W + c4 * 4);
    }
    __syncthreads();

    // ---- Phase 1: stage-1 (k=3) from LDS. 100 windows per supertile;
    // lane ln handles window ln and (ln<36) window 64+ln of ITS wave's tile.
#pragma unroll
    for (int b = 0; b < 2; ++b) {
        const int win = b * 64 + ln;
        if (win < 100) {
            const int wr = win / 10, wc = win - (win / 10) * 10;
            const int col0 = w * 30 + wc * 3;
            float mx = -1.0f;
            int am = 0;
#pragma unroll
            for (int r = 0; r < 3; ++r) {
                const int rr = wr * 3 + r;
                const float* p = &tile[rr * TW + col0];
                const float v0 = p[0], v1 = p[1], v2 = p[2];
                const int cc = wc * 3;
                if (v0 > mx) { mx = v0; am = (rr << 5) | cc; }
                if (v1 > mx) { mx = v1; am = (rr << 5) | (cc + 1); }
                if (v2 > mx) { mx = v2; am = (rr << 5) | (cc + 2); }
            }
            sv[w][win] = mx;
            sp[w][win] = am;
        }
    }

    // ---- Phase 1b: wave-local zero of this wave's 30-col stripe (float2,
    // 8B-aligned since 30w*4 = 120B multiples). Same wave read it above ->
    // LDS ops from one wave complete in order; barrier below covers doubt.
    for (int i = ln; i < 450; i += 64) {
        const int r = i / 15, c2 = i - (i / 15) * 15;
        *reinterpret_cast<float2*>(&tile[r * TW + w * 30 + c2 * 2]) =
            make_float2(0.f, 0.f);
    }
    __syncthreads();

    // ---- Phase 2: stage-2 (k=5). 36 cells/supertile, lanes 0..35.
    if (ln < 36) {
        const int a = ln / 6, b = ln - (ln / 6) * 6;
        const int rlo = (5 * a) / 3, rhi = (5 * a + 4) / 3;
        const int clo = (5 * b) / 3, chi = (5 * b + 4) / 3;
        float bv = -1.0f;
        int bp = 0x7FFFFFFF;
        for (int r3 = rlo; r3 <= rhi; ++r3)
            for (int c3 = clo; c3 <= chi; ++c3) {
                const int idx = r3 * 10 + c3;
                const float v = sv[w][idx];
                const int p = sp[w][idx];
                const int r = p >> 5, c = p & 31;
                const bool in =
                    ((unsigned)(r - 5 * a) < 5u) & ((unsigned)(c - 5 * b) < 5u);
                if (in && (v > bv || (v == bv && p < bp))) { bv = v; bp = p; }
            }
        w5v[w][ln] = bv;  // -1 if cell empty
        w5p[w][ln] = bp;
    }
    __syncthreads();

    // ---- Phase 3: stage-3 (k=6). 25 cells/supertile, lanes 0..24; exactly
    // 4 candidate 5-cells each; winners scatter into this wave's stripe.
    if (ln < 25) {
        const int a = ln / 5, b = ln - (ln / 5) * 5;
        const int rlo = (6 * a) / 5, clo = (6 * b) / 5;
        float bv = -1.0f;
        int bp = 0x7FFFFFFF;
#pragma unroll
        for (int dr = 0; dr < 2; ++dr)
#pragma unroll
            for (int dc = 0; dc < 2; ++dc) {
                const int idx = (rlo + dr) * 6 + (clo + dc);
                const float v = w5v[w][idx];
                const int p = w5p[w][idx];
                const int r = p >> 5, c = p & 31;
                const bool in = (v >= 0.0f) &
                                ((unsigned)(r - 6 * a) < 6u) &
                                ((unsigned)(c - 6 * b) < 6u);
                if (in && (v > bv || (v == bv && p < bp))) { bv = v; bp = p; }
            }
        if (bv >= 0.0f) tile[(bp >> 5) * TW + w * 30 + (bp & 31)] = bv;
    }
    __syncthreads();

    // ---- Phase 4: cooperative float4 store, LDS -> global. Fully coalesced.
    for (int i = t; i < 900; i += NT) {
        const int r = i / 30, c4 = i - (i / 30) * 30;
        *reinterpret_cast<float4*>(dst + (size_t)r * IMG_W + c4 * 4) = tile4[i];
    }
}

extern "C" void kernel_launch(void* const* d_in, const int* in_sizes, int n_in,
                              void* d_out, int out_size, void* d_ws, size_t ws_size,
                              hipStream_t stream) {
    const float* x = (const float*)d_in[0];
    float* out = (float*)d_out;
    dim3 grid(IMG_W / TW, IMG_H / 30, 16);  // 16 x 36 x 16 = 9216 blocks
    pooling_nms_kernel<<<grid, NT, 0, stream>>>(x, out);
}